// Round 2
// baseline (466.016 us; speedup 1.0000x reference)
//
#include <hip/hip_runtime.h>

// BlockCore: y[r, 4g+j] = sum_k blocks[g][j][k] * x[r, 4g+k]  for g<1024
//            y[r, 4096+i] = diag[i] * x[r, 4096+i]            for i<3
// rows r = B*T = 16384, ROW = 4099 floats (rows only 4B-aligned!)
constexpr int ROW      = 4099;
constexpr int ROWS     = 16384;
constexpr int GCH      = 64;               // blocks (groups) per workgroup
constexpr int NGCH     = 1024 / GCH;       // 16 group-chunks
constexpr int RCH      = 128;              // rows per workgroup
constexpr int NRCH     = ROWS / RCH;       // 128 row-chunks
// grid = NGCH * NRCH = 2048 workgroups (8/CU, 32 waves/CU)

__global__ __launch_bounds__(256) void blockcore_main(
    const float* __restrict__ x,
    const float* __restrict__ blocks,
    float* __restrict__ y)
{
    const int gchunk = blockIdx.x & (NGCH - 1);
    const int rchunk = blockIdx.x >> 4;          // log2(NGCH) = 4
    const int t = threadIdx.x;
    const int q = t >> 2;                         // 0..63: which block in chunk
    const int j = t & 3;                          // output row within 4x4 block
    const int g = gchunk * GCH + q;               // global block index

    // This thread's 4x4-block row lives in registers for the whole row loop.
    // blocks base is 256B-aligned; offset is a multiple of 16B -> float4 OK.
    const float4 b = *reinterpret_cast<const float4*>(blocks + (size_t)g * 16 + (size_t)j * 4);

    // Quad-uniform x pointer (4 lanes of a quad share addresses -> broadcast),
    // lane-consecutive y pointer (fully coalesced stores).
    const float* xp = x + (size_t)rchunk * RCH * ROW + (size_t)4 * g;
    float*       yp = y + (size_t)rchunk * RCH * ROW + (size_t)4 * g + j;

    #pragma unroll 4
    for (int r = 0; r < RCH; ++r) {
        const float x0 = xp[0];
        const float x1 = xp[1];
        const float x2 = xp[2];
        const float x3 = xp[3];
        *yp = b.x * x0 + b.y * x1 + b.z * x2 + b.w * x3;
        xp += ROW;
        yp += ROW;
    }
}

__global__ __launch_bounds__(256) void blockcore_rem(
    const float* __restrict__ x,
    const float* __restrict__ diag,
    float* __restrict__ y)
{
    const int idx = blockIdx.x * 256 + threadIdx.x;
    if (idx >= ROWS * 3) return;
    const int r = idx / 3;                        // magic-multiply
    const int i = idx - r * 3;
    const size_t off = (size_t)r * ROW + 4096 + i;
    y[off] = x[off] * diag[i];
}

extern "C" void kernel_launch(void* const* d_in, const int* in_sizes, int n_in,
                              void* d_out, int out_size, void* d_ws, size_t ws_size,
                              hipStream_t stream) {
    const float* x      = (const float*)d_in[0];
    const float* blocks = (const float*)d_in[1];
    const float* diag   = (const float*)d_in[2];
    float*       y      = (float*)d_out;

    blockcore_main<<<dim3(NGCH * NRCH), dim3(256), 0, stream>>>(x, blocks, y);
    blockcore_rem<<<dim3((ROWS * 3 + 255) / 256), dim3(256), 0, stream>>>(x, diag, y);
}